// Round 1
// baseline (4218.973 us; speedup 1.0000x reference)
//
#include <hip/hip_runtime.h>
#include <hip/hip_bf16.h>

#define BQ 256          // number of queries
#define NK 131072       // number of keys
#define DIM 128         // feature dim
#define QB 32           // queries per block (phase 1)
#define CHUNKS 64       // key chunks
#define CH (NK / CHUNKS)   // 2048 keys per chunk
#define KT 256             // keys per tile (== blockDim)
#define TILES (CH / KT)    // 8
#define KCAP 64            // top-k capacity (K<=64)
#define DELTA 1e-3f
#define PADF 3.0e38f

// ---------------- Phase 1: distances + per-(query,chunk) top-K ----------------
__global__ __launch_bounds__(256, 2)
void knn_phase1(const float* __restrict__ qkey,
                const float* __restrict__ keys,
                const float* __restrict__ values,
                const int* __restrict__ pK,
                float2* __restrict__ lists)
{
    __shared__ float  lq[QB][DIM];          // 16 KB, read uniform (broadcast)
    __shared__ float  qsq[QB];
    __shared__ float  dbuf[QB][KT + 1];     // padded stride 257 -> owner scans conflict-free
    __shared__ float  vals[KT];
    __shared__ float2 lst[QB][KCAP + 1];    // padded stride 65 float2 -> owners on distinct banks

    const int tid   = threadIdx.x;
    const int bid   = blockIdx.x;
    const int chunk = bid >> 3;       // 0..63
    const int qg    = bid & 7;        // 0..7
    const int q0    = qg * QB;

    int K = *pK;
    if (K < 1) K = 1;
    if (K > KCAP) K = KCAP;

    // stage queries (coalesced float4)
    {
        const float4* src = reinterpret_cast<const float4*>(qkey + (size_t)q0 * DIM);
        float4* dst = reinterpret_cast<float4*>(&lq[0][0]);
        for (int i = tid; i < QB * (DIM / 4); i += 256) dst[i] = src[i];
    }
    __syncthreads();
    // query squared norms + list init
    if (tid < QB) {
        float s = 0.f;
        const float4* row = reinterpret_cast<const float4*>(&lq[tid][0]);
        #pragma unroll
        for (int i = 0; i < DIM / 4; ++i) {
            float4 v = row[i];
            s = fmaf(v.x, v.x, s); s = fmaf(v.y, v.y, s);
            s = fmaf(v.z, v.z, s); s = fmaf(v.w, v.w, s);
        }
        qsq[tid] = s;
    }
    for (int i = tid; i < QB * KCAP; i += 256) {
        int q = i >> 6, s = i & (KCAP - 1);
        lst[q][s] = make_float2(PADF, 0.f);
    }
    __syncthreads();

    const int kbase = chunk * CH;
    for (int t = 0; t < TILES; ++t) {
        const int kidx = kbase + t * KT + tid;

        // key row -> 128 VGPRs
        float4 kr[32];
        const float4* kp = reinterpret_cast<const float4*>(keys + (size_t)kidx * DIM);
        #pragma unroll
        for (int i = 0; i < 32; ++i) kr[i] = kp[i];
        vals[tid] = values[kidx];

        float ksq = 0.f;
        {
            float a = 0.f, b = 0.f, c = 0.f, d = 0.f;
            #pragma unroll
            for (int i = 0; i < 32; ++i) {
                a = fmaf(kr[i].x, kr[i].x, a);
                b = fmaf(kr[i].y, kr[i].y, b);
                c = fmaf(kr[i].z, kr[i].z, c);
                d = fmaf(kr[i].w, kr[i].w, d);
            }
            ksq = (a + b) + (c + d);
        }

        // 32 dots: uniform LDS broadcast reads, 4 independent FMA chains
        #pragma unroll 2
        for (int q = 0; q < QB; ++q) {
            const float4* qrow = reinterpret_cast<const float4*>(&lq[q][0]);
            float ax = 0.f, ay = 0.f, az = 0.f, aw = 0.f;
            #pragma unroll
            for (int i = 0; i < 32; ++i) {
                float4 qv = qrow[i];
                ax = fmaf(kr[i].x, qv.x, ax);
                ay = fmaf(kr[i].y, qv.y, ay);
                az = fmaf(kr[i].z, qv.z, az);
                aw = fmaf(kr[i].w, qv.w, aw);
            }
            float dot  = (ax + ay) + (az + aw);
            float dist = fmaxf(qsq[q] + ksq - 2.f * dot, 0.f);
            dbuf[q][tid] = dist;
        }
        __syncthreads();

        // selection: 32 owners, 8 per wave (tid % 8 == 0)
        if ((tid & 7) == 0) {
            const int q = tid >> 3;
            float2* L = &lst[q][0];
            float thr = L[K - 1].x;
            #pragma unroll 1
            for (int i = 0; i < KT; ++i) {
                float d = dbuf[q][i];
                if (d < thr) {
                    float v = vals[i];
                    int j = K - 1;
                    while (j > 0 && L[j - 1].x > d) { L[j] = L[j - 1]; --j; }
                    L[j] = make_float2(d, v);
                    thr = L[K - 1].x;
                }
            }
        }
        __syncthreads();
    }

    // write lists (K real entries, rest PADF) to workspace
    for (int i = tid; i < QB * KCAP; i += 256) {
        int q = i >> 6, s = i & (KCAP - 1);
        lists[(((size_t)(q0 + q)) * CHUNKS + chunk) * KCAP + s] = lst[q][s];
    }
}

// ---------------- Phase 2: merge 64 chunk-lists -> exact top-K weighted mean ----------------
__global__ __launch_bounds__(256, 4)
void knn_phase2(const float2* __restrict__ lists,
                const int* __restrict__ pK,
                float* __restrict__ out)
{
    const int gq  = blockIdx.x;
    const int tid = threadIdx.x;
    int K = *pK;
    if (K < 1) K = 1;
    if (K > KCAP) K = KCAP;

    const int TOT = CHUNKS * KCAP;   // 4096
    const int PER = TOT / 256;       // 16

    float2 e[PER];
    unsigned eb[PER];
    const float2* src = lists + (size_t)gq * TOT;
    #pragma unroll
    for (int i = 0; i < PER; ++i) {
        e[i]  = src[tid + 256 * i];                 // coalesced
        eb[i] = __float_as_uint(e[i].x);            // dist >= 0 -> bits monotone
    }

    __shared__ int      red[4];
    __shared__ unsigned bcast;

    // binary search for K-th smallest distance (bit pattern T)
    unsigned lo = 0u, hi = 0x7f7fffffu;             // [0, FLT_MAX]
    while (lo < hi) {
        unsigned mid = lo + ((hi - lo) >> 1);
        int c = 0;
        #pragma unroll
        for (int i = 0; i < PER; ++i) c += (eb[i] <= mid) ? 1 : 0;
        #pragma unroll
        for (int off = 32; off; off >>= 1) c += __shfl_down(c, off, 64);
        if ((tid & 63) == 0) red[tid >> 6] = c;
        __syncthreads();
        if (tid == 0) {
            int tot = red[0] + red[1] + red[2] + red[3];
            bcast = (tot >= K) ? 1u : 0u;
        }
        __syncthreads();
        if (bcast) hi = mid; else lo = mid + 1;
        __syncthreads();
    }
    const unsigned T = lo;

    // weighted sums; ties at T averaged deterministically
    float sw = 0.f, swv = 0.f, sev = 0.f;
    int cl = 0, ce = 0;
    #pragma unroll
    for (int i = 0; i < PER; ++i) {
        unsigned b = eb[i];
        if (b < T) {
            float w = 1.0f / (e[i].x + DELTA);
            cl += 1; sw += w; swv = fmaf(w, e[i].y, swv);
        } else if (b == T) {
            ce += 1; sev += e[i].y;
        }
    }
    #pragma unroll
    for (int off = 32; off; off >>= 1) {
        sw  += __shfl_down(sw,  off, 64);
        swv += __shfl_down(swv, off, 64);
        sev += __shfl_down(sev, off, 64);
        cl  += __shfl_down(cl,  off, 64);
        ce  += __shfl_down(ce,  off, 64);
    }
    __shared__ float rsw[4], rswv[4], rsev[4];
    __shared__ int   rcl[4], rce[4];
    const int wid = tid >> 6;
    if ((tid & 63) == 0) { rsw[wid] = sw; rswv[wid] = swv; rsev[wid] = sev; rcl[wid] = cl; rce[wid] = ce; }
    __syncthreads();
    if (tid == 0) {
        float SW = 0.f, SWV = 0.f, SEV = 0.f; int CL = 0, CE = 0;
        #pragma unroll
        for (int i = 0; i < 4; ++i) { SW += rsw[i]; SWV += rswv[i]; SEV += rsev[i]; CL += rcl[i]; CE += rce[i]; }
        float dT   = __uint_as_float(T);
        float wT   = 1.0f / (dT + DELTA);
        float need = (float)(K - CL);               // >= 1 by construction
        float num  = SWV + wT * SEV * (need / (float)CE);
        float den  = SW + wT * need;
        out[gq] = num / den;
    }
}

extern "C" void kernel_launch(void* const* d_in, const int* in_sizes, int n_in,
                              void* d_out, int out_size, void* d_ws, size_t ws_size,
                              hipStream_t stream) {
    const float* qkey   = (const float*)d_in[0];   // [B, D]
    const float* keys   = (const float*)d_in[1];   // [N, D]
    const float* values = (const float*)d_in[2];   // [N, 1]
    const int*   pK     = (const int*)d_in[3];     // scalar K
    float*  out   = (float*)d_out;                 // [B, 1]
    float2* lists = (float2*)d_ws;                 // [B][CHUNKS][KCAP] (dist,value) = 8.4 MB

    knn_phase1<<<dim3(CHUNKS * (BQ / QB)), dim3(256), 0, stream>>>(qkey, keys, values, pK, lists);
    knn_phase2<<<dim3(BQ), dim3(256), 0, stream>>>(lists, pK, out);
}

// Round 2
// 214.262 us; speedup vs baseline: 19.6907x; 19.6907x over previous
//
#include <hip/hip_runtime.h>
#include <hip/hip_bf16.h>

#define BQ 256
#define NK 131072
#define DIM 128
#define QTILE 32
#define KTILE 256
#define NCH (NK / KTILE)     // 512 chunk-blocks along N
#define DELTA 1e-3f

#define NB 8192              // radix bins (float bits >> 18)
#define SHIFT 18
#define CAP 2048             // boundary-bin candidate capacity

// ---------------- Phase 1: dist[q][n] = max(|q|^2+|k|^2-2 q.k, 0) ----------------
// 256 threads, tile 32q x 256k, per-thread 4q x 8k, D in 8-wide LDS chunks.
__global__ __launch_bounds__(256, 4)
void p1_dist(const float* __restrict__ qkey,
             const float* __restrict__ keys,
             float* __restrict__ dist,
             int q0, int nq, int qg_n)
{
    __shared__ __align__(16) float lq[QTILE][DIM];   // 16 KB, wave-broadcast reads
    __shared__ float4 kt4[2*KTILE];                  // 8 KB, [j][k] layout (bank-optimal kf reads)
    __shared__ float  qsq_s[QTILE];
    __shared__ float  ksq_s[KTILE];

    const int tid   = threadIdx.x;
    const int chunk = blockIdx.x / qg_n;             // consecutive bids share chunk
    const int qg    = blockIdx.x % qg_n;
    const int qbase = q0 + qg * QTILE;

    // stage queries (coalesced float4, clamped for partial slabs)
    {
        const float4* qsrc = (const float4*)qkey;
        #pragma unroll
        for (int i = 0; i < 4; ++i) {
            int r  = tid + 256 * i;                  // 0..1023
            int qq = r >> 5;
            int c  = r & 31;
            int qglob = qbase + qq; if (qglob > BQ - 1) qglob = BQ - 1;
            ((float4*)lq)[r] = qsrc[qglob * (DIM/4) + c];
        }
    }
    __syncthreads();
    if (tid < QTILE) {
        const float4* qr = (const float4*)&lq[tid][0];
        float a = 0.f, b = 0.f, c = 0.f, d = 0.f;
        #pragma unroll
        for (int i = 0; i < DIM/4; ++i) {
            float4 v = qr[i];
            a = fmaf(v.x, v.x, a); b = fmaf(v.y, v.y, b);
            c = fmaf(v.z, v.z, c); d = fmaf(v.w, v.w, d);
        }
        qsq_s[tid] = (a + b) + (c + d);
    }

    const int kbase = chunk * KTILE;
    const float4* kp4 = (const float4*)keys + (size_t)kbase * (DIM/4);

    float acc[4][8];
    #pragma unroll
    for (int a1 = 0; a1 < 4; ++a1)
        #pragma unroll
        for (int b1 = 0; b1 < 8; ++b1) acc[a1][b1] = 0.f;
    float ksq_acc = 0.f;

    const int klane = tid & 31, qsel = tid >> 5;

    #pragma unroll 1
    for (int t = 0; t < DIM/8; ++t) {
        // issue next-chunk global loads before the barrier (latency hides under other waves)
        float4 va = kp4[(size_t)(tid >> 1) * (DIM/4) + t*2 + (tid & 1)];
        float4 vb = kp4[(size_t)((tid >> 1) + 128) * (DIM/4) + t*2 + (tid & 1)];
        __syncthreads();                             // previous chunk's compute done
        kt4[(tid & 1) * KTILE + (tid >> 1)]       = va;
        kt4[(tid & 1) * KTILE + (tid >> 1) + 128] = vb;
        __syncthreads();
        // ksq partial for row k = tid
        {
            float4 x = kt4[tid], y = kt4[KTILE + tid];
            ksq_acc += ((x.x*x.x + x.y*x.y) + (x.z*x.z + x.w*x.w))
                     + ((y.x*y.x + y.y*y.y) + (y.z*y.z + y.w*y.w));
        }
        #pragma unroll
        for (int j = 0; j < 2; ++j) {
            float4 kf[8];
            #pragma unroll
            for (int kk = 0; kk < 8; ++kk) kf[kk] = kt4[j*KTILE + klane + 32*kk];
            float4 qf[4];
            #pragma unroll
            for (int qq = 0; qq < 4; ++qq) qf[qq] = *(const float4*)&lq[qsel*4 + qq][t*8 + 4*j];
            #pragma unroll
            for (int qq = 0; qq < 4; ++qq)
                #pragma unroll
                for (int kk = 0; kk < 8; ++kk) {
                    float s = acc[qq][kk];
                    s = fmaf(qf[qq].x, kf[kk].x, s);
                    s = fmaf(qf[qq].y, kf[kk].y, s);
                    s = fmaf(qf[qq].z, kf[kk].z, s);
                    s = fmaf(qf[qq].w, kf[kk].w, s);
                    acc[qq][kk] = s;
                }
        }
    }
    ksq_s[tid] = ksq_acc;
    __syncthreads();

    #pragma unroll
    for (int qq = 0; qq < 4; ++qq) {
        int qrel = qg * QTILE + qsel*4 + qq;
        if (qrel < nq) {
            float qs = qsq_s[qsel*4 + qq];
            float* drow = dist + (size_t)qrel * NK + kbase;
            #pragma unroll
            for (int kk = 0; kk < 8; ++kk) {
                int k = klane + 32*kk;                            // coalesced per half-wave
                drow[k] = fmaxf(qs + ksq_s[k] - 2.f * acc[qq][kk], 0.f);
            }
        }
    }
}

// ---------------- Phase 2: radix-select K-th smallest + weighted mean ----------------
__global__ __launch_bounds__(1024, 1)
void p2_select(const float* __restrict__ dist,
               const float* __restrict__ values,
               const int* __restrict__ pK,
               float* __restrict__ out)
{
    const int tid  = threadIdx.x;
    const int lane = tid & 63;
    const int wid  = tid >> 6;
    const float4* row4 = (const float4*)(dist + (size_t)blockIdx.x * NK);

    int K = *pK; if (K < 1) K = 1; if (K > NK) K = NK;

    __shared__ int   hist[NB];       // 32 KB
    __shared__ uint2 list[CAP];      // 16 KB (bits, value)
    __shared__ int   lcount, s_bb, s_cb;
    __shared__ int   iscan[16];
    __shared__ float fred[48];

    for (int i = tid; i < NB; i += 1024) hist[i] = 0;
    if (tid == 0) { lcount = 0; s_bb = NB - 1; s_cb = 0; }
    __syncthreads();

    // pass A: histogram (integer atomics -> deterministic)
    for (int i = 0; i < NK/4096; ++i) {
        float4 v = row4[tid + 1024*i];
        atomicAdd(&hist[__float_as_uint(v.x) >> SHIFT], 1);
        atomicAdd(&hist[__float_as_uint(v.y) >> SHIFT], 1);
        atomicAdd(&hist[__float_as_uint(v.z) >> SHIFT], 1);
        atomicAdd(&hist[__float_as_uint(v.w) >> SHIFT], 1);
    }
    __syncthreads();

    // block scan over 8192 bins (8 per thread) -> boundary bin bb, exact count below
    int h[8], s = 0;
    #pragma unroll
    for (int b = 0; b < 8; ++b) { h[b] = hist[tid*8 + b]; s += h[b]; }
    int incl = s;
    #pragma unroll
    for (int off = 1; off < 64; off <<= 1) {
        int t = __shfl_up(incl, off, 64);
        if (lane >= off) incl += t;
    }
    if (lane == 63) iscan[wid] = incl;
    __syncthreads();
    if (tid == 0) { int c = 0; for (int w = 0; w < 16; ++w) { int t = iscan[w]; iscan[w] = c; c += t; } }
    __syncthreads();
    int base = iscan[wid] + (incl - s);
    if (base < K && K <= base + s) {
        int c = base;
        #pragma unroll
        for (int b = 0; b < 8; ++b) {
            if (c < K && c + h[b] >= K) { s_bb = tid*8 + b; s_cb = c; }
            c += h[b];
        }
    }
    __syncthreads();
    const int bb = s_bb, cbelow = s_cb, R = K - cbelow, CEall = hist[bb];

    // pass B: sums below boundary bin (deterministic tree) + boundary candidates
    float sw = 0.f, swv = 0.f, seva = 0.f;
    for (int i = 0; i < NK/4096; ++i) {
        float4 v = row4[tid + 1024*i];
        int n0 = (tid + 1024*i) * 4;
        float dd[4] = { v.x, v.y, v.z, v.w };
        #pragma unroll
        for (int c = 0; c < 4; ++c) {
            unsigned bts = __float_as_uint(dd[c]);
            int bin = (int)(bts >> SHIFT);
            if (bin < bb) {
                float w = 1.f / (dd[c] + DELTA);
                float vv = values[n0 + c];
                sw += w; swv = fmaf(w, vv, swv);
            } else if (bin == bb) {
                float vv = values[n0 + c];
                seva += vv;
                int sl = atomicAdd(&lcount, 1);
                if (sl < CAP) list[sl] = make_uint2(bts, __float_as_uint(vv));
            }
        }
    }
    #pragma unroll
    for (int off = 32; off; off >>= 1) {
        sw   += __shfl_down(sw,   off, 64);
        swv  += __shfl_down(swv,  off, 64);
        seva += __shfl_down(seva, off, 64);
    }
    if (lane == 0) { fred[wid] = sw; fred[16 + wid] = swv; fred[32 + wid] = seva; }
    __syncthreads();

    if (wid == 0) {
        float SW = 0.f, SWV = 0.f, SEVA = 0.f;
        for (int w = 0; w < 16; ++w) { SW += fred[w]; SWV += fred[16 + w]; SEVA += fred[32 + w]; }
        const int L = lcount;
        double num, den;
        if (L <= CAP) {
            // exact K-th bit pattern among boundary candidates (integer, deterministic)
            unsigned lo = ((unsigned)bb) << SHIFT;
            unsigned hi = lo + ((1u << SHIFT) - 1u);
            while (lo < hi) {
                unsigned mid = lo + ((hi - lo) >> 1);
                int c = 0;
                for (int i = lane; i < L; i += 64) c += (list[i].x <= mid) ? 1 : 0;
                #pragma unroll
                for (int off = 32; off; off >>= 1) c += __shfl_xor(c, off, 64);
                if (c >= R) hi = mid; else lo = mid + 1;
            }
            const unsigned T = lo;
            int cl2 = 0, ce = 0;
            double swl = 0.0, swvl = 0.0, sevt = 0.0;   // f64: order-noise ~1e-16
            for (int i = lane; i < L; i += 64) {
                unsigned b = list[i].x;
                float vv = __uint_as_float(list[i].y);
                if (b < T) {
                    double w = 1.0 / ((double)__uint_as_float(b) + (double)DELTA);
                    cl2 += 1; swl += w; swvl += w * (double)vv;
                } else if (b == T) { ce += 1; sevt += (double)vv; }
            }
            #pragma unroll
            for (int off = 32; off; off >>= 1) {
                cl2  += __shfl_xor(cl2,  off, 64);
                ce   += __shfl_xor(ce,   off, 64);
                swl  += __shfl_xor(swl,  off, 64);
                swvl += __shfl_xor(swvl, off, 64);
                sevt += __shfl_xor(sevt, off, 64);
            }
            const int need = R - cl2;                 // >=1, <= ce
            double wT = 1.0 / ((double)__uint_as_float(T) + (double)DELTA);
            num = (double)SWV + swvl + wT * ((double)need / (double)ce) * sevt;
            den = (double)SW  + swl  + wT * (double)need;
        } else {
            // degenerate overflow: >CAP near-equal dists in one bin -> treat as tied at bin edge
            double wT = 1.0 / ((double)__uint_as_float(((unsigned)bb) << SHIFT) + (double)DELTA);
            num = (double)SWV + wT * ((double)R / (double)CEall) * (double)SEVA;
            den = (double)SW  + wT * (double)R;
        }
        if (lane == 0) out[blockIdx.x] = (float)(num / den);
    }
}

extern "C" void kernel_launch(void* const* d_in, const int* in_sizes, int n_in,
                              void* d_out, int out_size, void* d_ws, size_t ws_size,
                              hipStream_t stream)
{
    const float* qkey   = (const float*)d_in[0];
    const float* keys   = (const float*)d_in[1];
    const float* values = (const float*)d_in[2];
    const int*   pK     = (const int*)d_in[3];
    float* out  = (float*)d_out;
    float* dist = (float*)d_ws;

    const size_t rowb = (size_t)NK * sizeof(float);
    int slabQ;
    if (ws_size >= (size_t)BQ * rowb) slabQ = BQ;
    else {
        int rows = (int)(ws_size / rowb);
        slabQ = (rows / QTILE) * QTILE;
        if (slabQ < QTILE) slabQ = 16;   // 16 rows = 8.4 MB, proven to fit in round 1
    }
    for (int q0 = 0; q0 < BQ; q0 += slabQ) {
        int nq = BQ - q0; if (nq > slabQ) nq = slabQ;
        int qg_n = (nq + QTILE - 1) / QTILE;
        p1_dist<<<dim3(NCH * qg_n), dim3(256), 0, stream>>>(qkey, keys, dist, q0, nq, qg_n);
        p2_select<<<dim3(nq), dim3(1024), 0, stream>>>(dist, values, pK, out + q0);
    }
}